// Round 4
// baseline (1414.568 us; speedup 1.0000x reference)
//
#include <hip/hip_runtime.h>
#include <hip/hip_bf16.h>

// Problem constants (from reference): L layers, B batch, D width.
constexpr int L = 8;
constexpr int B = 32;
constexpr int D = 1280;

constexpr int JT = 64;              // output columns per block (256B/wave-instr, contiguous)
constexpr int ISPLIT = 4;           // i-reduction split across the block's 4 waves
constexpr int BLOCK = JT * ISPLIT;  // 256 threads
constexpr int ICHUNK = D / ISPLIT;  // 320
constexpr int NBB = D / JT;         // 20 blocks per batch
constexpr int PF = 16;              // next-layer W prefetch depth (regs/thread)

// Persistent kernel, grid = (20, 32) = 640 blocks. Inter-layer sync is
// PER-BATCH: each batch's 20 blocks rendezvous on an agent-scope counter.
// Safe without cooperative launch: a batch's blocks are consecutive in
// dispatch order and depend only on each other, so batches pipeline and
// retire independently (no grid-wide co-residency requirement).
__global__ __launch_bounds__(BLOCK) void fused_kernel(
    const float* __restrict__ x,     // [B, D]
    const float* __restrict__ Wall,  // [L, B, D, D]
    const float* __restrict__ ball,  // [L, B, D]
    const int*   __restrict__ mall,  // [L, B, D]
    float*       __restrict__ out,   // [B, D]
    float*       __restrict__ ws0,   // [B, D] h ping
    float*       __restrict__ ws1,   // [B, D] h pong
    int*         __restrict__ cnt)   // [L, B] barrier counters (zeroed per call)
{
    const int b  = blockIdx.y;
    const int j0 = blockIdx.x * JT;
    const int t  = threadIdx.x;
    const int jj = t & (JT - 1);   // 0..63
    const int iq = t >> 6;         // 0..3
    const int j  = j0 + jj;
    const int i_beg = iq * ICHUNK;

    __shared__ float hs[D];
    __shared__ float partial[BLOCK];

    const float* hin = x;
    const float* w = Wall + (size_t)b * D * D + j;

    // Prefetch first PF W rows of layer 0 (independent of h).
    float pf[PF];
#pragma unroll
    for (int k = 0; k < PF; ++k) pf[k] = w[(size_t)(i_beg + k) * D];

    for (int l = 0; l < L; ++l) {
        float* hout = (l == L - 1) ? out : ((l & 1) ? ws1 : ws0);

        // Stage h[b,:] into LDS (float4, coalesced; broadcast reads later).
        {
            const float4* src = (const float4*)(hin + b * D);
            float4* dst = (float4*)hs;
            for (int k = t; k < D / 4; k += BLOCK) dst[k] = src[k];
        }
        __syncthreads();

        // i-reduction: first PF iters consume prefetched regs, rest stream.
        float acc = 0.f;
#pragma unroll
        for (int k = 0; k < PF; ++k) acc = fmaf(hs[i_beg + k], pf[k], acc);
#pragma unroll 16
        for (int i = i_beg + PF; i < i_beg + ICHUNK; ++i)
            acc = fmaf(hs[i], w[(size_t)i * D], acc);

        partial[t] = acc;
        __syncthreads();

        if (t < JT) {
            float s = partial[t] + partial[t + 64] + partial[t + 128] + partial[t + 192];
            const int idx = b * D + j0 + t;
            const size_t lidx = (size_t)l * B * D + idx;
            s += ball[lidx];
            if (mall[lidx]) s = fmaxf(s, 0.f);
            hout[idx] = s;
        }

        if (l + 1 < L) {
            // ---- per-batch barrier: publish our h chunk, wait for the batch ----
            __threadfence();     // make hout stores visible at agent scope
            __syncthreads();     // all waves' stores are fenced before signaling
            if (t == 0)
                __hip_atomic_fetch_add(&cnt[l * B + b], 1,
                                       __ATOMIC_RELEASE, __HIP_MEMORY_SCOPE_AGENT);

            // Prefetch next layer's W while spinning (keeps HBM streaming
            // through the barrier; these loads don't depend on h).
            const float* wn = Wall + ((size_t)(l + 1) * B + b) * D * D + j;
#pragma unroll
            for (int k = 0; k < PF; ++k) pf[k] = wn[(size_t)(i_beg + k) * D];
            w = wn;

            if (t == 0) {
                while (__hip_atomic_load(&cnt[l * B + b],
                                         __ATOMIC_ACQUIRE, __HIP_MEMORY_SCOPE_AGENT) < NBB)
                    __builtin_amdgcn_s_sleep(1);
            }
            __syncthreads();     // acquire by t0 (same CU) + block barrier
            hin = hout;
        }
    }
}

extern "C" void kernel_launch(void* const* d_in, const int* in_sizes, int n_in,
                              void* d_out, int out_size, void* d_ws, size_t ws_size,
                              hipStream_t stream) {
    const float* x       = (const float*)d_in[0];  // [B, D]
    const float* weights = (const float*)d_in[1];  // [L, B, D, D]
    const float* biases  = (const float*)d_in[2];  // [L, B, D]
    const int*   masks   = (const int*)  d_in[3];  // [L, B, D]
    float* out = (float*)d_out;                    // [B, D]

    float* ws0 = (float*)d_ws;
    float* ws1 = ws0 + B * D;
    int*   cnt = (int*)(ws1 + B * D);              // [L, B]

    // Barrier counters must be zero at kernel start, every call (replays
    // don't re-poison d_ws). hipMemsetAsync is graph-capture-safe.
    hipMemsetAsync(cnt, 0, L * B * sizeof(int), stream);

    dim3 grid(D / JT, B);
    dim3 block(BLOCK);
    fused_kernel<<<grid, block, 0, stream>>>(x, weights, biases, masks,
                                             out, ws0, ws1, cnt);
}

// Round 5
// 378.926 us; speedup vs baseline: 3.7331x; 3.7331x over previous
//
#include <hip/hip_runtime.h>
#include <hip/hip_bf16.h>

// Problem constants (from reference): L layers, B batch, D width.
constexpr int L = 8;
constexpr int B = 32;
constexpr int D = 1280;

constexpr int JT = 64;              // output columns per tile (256B/wave-instr, contiguous)
constexpr int ISPLIT = 4;           // i-reduction split across the block's 4 waves
constexpr int BLOCK = JT * ISPLIT;  // 256 threads
constexpr int ICHUNK = D / ISPLIT;  // 320
constexpr int NBB = D / JT;         // 20 tiles per batch
constexpr int NT = NBB * B;         // 640 tiles per layer
constexpr int NSTATIC = 512;        // = grid size: exactly 2 blocks/CU on 256 CUs
constexpr int PF = 16;              // W prefetch depth for the first tile (regs/thread)

// One layer. grid = 512 blocks (2/CU, perfectly balanced). Each block computes
// its static tile (with entry W-prefetch to fill the HBM pipe immediately),
// then work-steals the remaining 128 tiles via a relaxed atomic counter.
// Tiles within a layer are independent -> no fences, deterministic results.
__global__ __launch_bounds__(BLOCK) void layer_kernel(
    const float* __restrict__ hin,   // [B, D]
    const float* __restrict__ W,     // [B, D, D]
    const float* __restrict__ bias,  // [B, D]
    const int*   __restrict__ mask,  // [B, D]
    float*       __restrict__ hout,  // [B, D]
    int*         __restrict__ steal) // one counter for this layer (zeroed per call)
{
    const int t  = threadIdx.x;
    const int jj = t & (JT - 1);   // 0..63
    const int iq = t >> 6;         // 0..3
    const int i_beg = iq * ICHUNK;

    __shared__ float hs[D];
    __shared__ float partial[BLOCK];
    __shared__ int   stile;

    // ---- static tile: prefetch W first (HBM busy from cycle ~0) ----
    {
        const int tile = blockIdx.x;
        const int b = tile / NBB, j0 = (tile % NBB) * JT;
        const float* w = W + (size_t)b * D * D + j0 + jj;

        float pf[PF];
#pragma unroll
        for (int k = 0; k < PF; ++k) pf[k] = w[(size_t)(i_beg + k) * D];

        const float4* src = (const float4*)(hin + b * D);
        float4* dst = (float4*)hs;
        for (int k = t; k < D / 4; k += BLOCK) dst[k] = src[k];
        __syncthreads();

        float acc = 0.f;
#pragma unroll
        for (int k = 0; k < PF; ++k) acc = fmaf(hs[i_beg + k], pf[k], acc);
#pragma unroll 16
        for (int i = i_beg + PF; i < i_beg + ICHUNK; ++i)
            acc = fmaf(hs[i], w[(size_t)i * D], acc);

        partial[t] = acc;
        __syncthreads();
        if (t < JT) {
            float s = partial[t] + partial[t + 64] + partial[t + 128] + partial[t + 192];
            const int idx = b * D + j0 + t;
            s += bias[idx];
            if (mask[idx]) s = fmaxf(s, 0.f);
            hout[idx] = s;
        }
    }

    // ---- work-steal the remaining NT - NSTATIC tiles ----
    for (;;) {
        __syncthreads();                       // protect partial/hs reuse
        if (t == 0) stile = NSTATIC + atomicAdd(steal, 1);  // relaxed, device scope
        __syncthreads();
        const int tile = stile;
        if (tile >= NT) break;

        const int b = tile / NBB, j0 = (tile % NBB) * JT;

        const float4* src = (const float4*)(hin + b * D);
        float4* dst = (float4*)hs;
        for (int k = t; k < D / 4; k += BLOCK) dst[k] = src[k];
        __syncthreads();

        const float* w = W + (size_t)b * D * D + j0 + jj;
        float acc = 0.f;
#pragma unroll 16
        for (int i = i_beg; i < i_beg + ICHUNK; ++i)
            acc = fmaf(hs[i], w[(size_t)i * D], acc);

        partial[t] = acc;
        __syncthreads();
        if (t < JT) {
            float s = partial[t] + partial[t + 64] + partial[t + 128] + partial[t + 192];
            const int idx = b * D + j0 + t;
            s += bias[idx];
            if (mask[idx]) s = fmaxf(s, 0.f);
            hout[idx] = s;
        }
    }
}

extern "C" void kernel_launch(void* const* d_in, const int* in_sizes, int n_in,
                              void* d_out, int out_size, void* d_ws, size_t ws_size,
                              hipStream_t stream) {
    const float* x       = (const float*)d_in[0];  // [B, D]
    const float* weights = (const float*)d_in[1];  // [L, B, D, D]
    const float* biases  = (const float*)d_in[2];  // [L, B, D]
    const int*   masks   = (const int*)  d_in[3];  // [L, B, D]
    float* out = (float*)d_out;                    // [B, D]

    float* ws0 = (float*)d_ws;
    float* ws1 = ws0 + B * D;
    int*   cnt = (int*)(ws1 + B * D);              // [L] steal counters

    // Zero the steal counters each call (replays don't re-poison d_ws).
    hipMemsetAsync(cnt, 0, L * sizeof(int), stream);

    dim3 grid(NSTATIC);
    dim3 block(BLOCK);

    const float* hin = x;
    for (int l = 0; l < L; ++l) {
        float* hout = (l == L - 1) ? out : ((l & 1) ? ws1 : ws0);
        layer_kernel<<<grid, block, 0, stream>>>(
            hin,
            weights + (size_t)l * B * D * D,
            biases  + (size_t)l * B * D,
            masks   + (size_t)l * B * D,
            hout,
            cnt + l);
        hin = hout;
    }
}